// Round 9
// baseline (2812.206 us; speedup 1.0000x reference)
//
#include <hip/hip_runtime.h>

// SolarRNN: B=256, T=4096, F=16, H=64. Two fused GRU layers + online-softmax
// attention + MLP tail. Block b = sequence b.
//
// R9: barrier-free LINEAR 4-stage pipeline, 256 thr = 4 waves (1/SIMD, full
// register budget), full K=64 in-lane everywhere (lane j = output col j):
//   W0: xg(t) = {x@Wi1r+bi1r, x@Wi1z+bi1z, x@Wi1n+bi1n, 0.5(x@Wp+bp)}.
//       Feed-forward only -> runs ~8 steps ahead. Also stages x chunks.
//   W1: L1 hidden (96 fl/gate, 48 pk-FMA) + pointwise -> h1, o1. h1
//       recurrence PRIVATE (LDS write -> in-order broadcast read, no flags).
//   W2: pin(t) = o1(t) @ Wi2 + bi2 (96 pk-FMA).
//   W3: L2 hidden + pointwise + online softmax fully in-wave (no skew).
// Flags: prog[i] = steps completed by wave i, monotone, FORWARD-ONLY chain
// W0->W1->W2->W3 (no cycles -> no deadlock). Back-pressure: amortized
// every-8-step polls with >=8-slack on 16-deep rings. Consumer protocol:
// poll flag, then asm memory clobber (blocks compiler value-caching/LICM,
// the R8 hazard), then reads (HW issues in program order). Producer:
// s_waitcnt lgkmcnt(0) then flag store. Polls guard-bounded (65536): a
// protocol bug yields finite-time wrong numerics, never a hang.
// Per-wave weights <=96 v2f (~230 VGPR) - inside the arch VGPR file.

#define B_ 256
#define T_ 4096
#define F_ 16
#define H_ 64
#define L2E 1.4426950408889634f
#define DEPTH 16
#define PGUARD 65536

typedef float v2f __attribute__((ext_vector_type(2)));

__device__ __forceinline__ float rdlane(float v, int lane) {
    return __builtin_bit_cast(float, __builtin_amdgcn_readlane(__builtin_bit_cast(int, v), lane));
}
__device__ __forceinline__ float sigm(float x) {
    float e = __builtin_amdgcn_exp2f(-L2E * x);
    return __builtin_amdgcn_rcpf(1.0f + e);
}
__device__ __forceinline__ float tanh_(float x) {
    float e = __builtin_amdgcn_exp2f(2.0f * L2E * x);
    return 1.0f - 2.0f * __builtin_amdgcn_rcpf(1.0f + e);
}
__device__ __forceinline__ v2f fma2(v2f a, v2f b, v2f c) {
    return __builtin_elementwise_fma(a, b, c);
}

#define DPPADD(x, ctrl) \
    ((x) + __builtin_bit_cast(float, __builtin_amdgcn_update_dpp( \
        0, __builtin_bit_cast(int, (x)), (ctrl), 0xF, 0xF, true)))

// full wave64 sum; total lands in lane 63 (verified R3-R7)
__device__ __forceinline__ float wred(float x) {
    x = DPPADD(x, 0x111);
    x = DPPADD(x, 0x112);
    x = DPPADD(x, 0x114);
    x = DPPADD(x, 0x118);
    x = DPPADD(x, 0x142);
    x = DPPADD(x, 0x143);
    return x;
}

#define LGKM0() asm volatile("s_waitcnt lgkmcnt(0)" ::: "memory")

// poll flag >= tgt; bounded (bug -> wrong numerics, not hang); the trailing
// memory clobber forces the compiler to reload LDS values after the wait.
__device__ __forceinline__ void waitge(volatile const int* f, int tgt) {
    if (*f < tgt) {
        int g = 0;
        do {
            __builtin_amdgcn_s_sleep(2);
            if (*f >= tgt) break;
        } while (++g < PGUARD);
    }
    asm volatile("" ::: "memory");
}

__launch_bounds__(256, 1)
__attribute__((amdgpu_waves_per_eu(1, 1)))
__global__ void solar_rnn(const float* __restrict__ x,
                          const float* __restrict__ Wi1, const float* __restrict__ bi1,
                          const float* __restrict__ Whr1, const float* __restrict__ Whz1,
                          const float* __restrict__ Whn1, const float* __restrict__ bhn1,
                          const float* __restrict__ Wi2, const float* __restrict__ bi2,
                          const float* __restrict__ Whr2, const float* __restrict__ Whz2,
                          const float* __restrict__ Whn2, const float* __restrict__ bhn2,
                          const float* __restrict__ Wp, const float* __restrict__ bp,
                          const float* __restrict__ Wa,
                          const float* __restrict__ W1, const float* __restrict__ b1,
                          const float* __restrict__ W2, const float* __restrict__ b2,
                          const float* __restrict__ W3, const float* __restrict__ b3,
                          const float* __restrict__ W4, const float* __restrict__ b4,
                          float* __restrict__ out)
{
    const int b   = blockIdx.x;
    const int tid = threadIdx.x;
    const int w   = tid >> 6;        // 0=xg, 1=L1, 2=pin, 3=L2+attn
    const int j   = tid & 63;        // lane = output col

    __shared__ __align__(16) float xsh[2][256];      // x chunks (W0-private)
    __shared__ float xg[DEPTH][4][64];               // W0 -> W1
    __shared__ float o1r[DEPTH][64];                 // W1 -> W2, W3
    __shared__ float pnr[DEPTH][3][64];              // W2 -> W3
    __shared__ __align__(16) float h1b[2][64];       // W1-private h1 broadcast
    __shared__ __align__(16) float h2b[2][64];       // W3-private h2 broadcast
    __shared__ int prog[4];
    __shared__ float sm_a[128];
    __shared__ float sm_b[128];
    volatile int* pv = prog;

    if (tid < 4) prog[tid] = 0;
    if (tid < 64) { h1b[1][tid] = 0.f; h2b[1][tid] = 0.f; }
    const float* xb = x + (size_t)b * T_ * F_;
    float4 xnext;
    if (w == 0) {
        ((float4*)&xsh[0][0])[j] = ((const float4*)xb)[j];   // chunk 0
        xnext = ((const float4*)xb)[64 + j];                 // chunk 1
    }
    __syncthreads();

    if (w == 0) {
        // ================= W0: input projections (runs ahead) =================
        v2f a1r[8], a1z[8], a1n[8], apv[8];
        #pragma unroll
        for (int m = 0; m < 8; ++m) {
            const int r0 = 2 * m, r1 = r0 + 1;
            a1r[m] = v2f{Wi1[r0 * 192 + j],        Wi1[r1 * 192 + j]};
            a1z[m] = v2f{Wi1[r0 * 192 + 64 + j],   Wi1[r1 * 192 + 64 + j]};
            a1n[m] = v2f{Wi1[r0 * 192 + 128 + j],  Wi1[r1 * 192 + 128 + j]};
            apv[m] = v2f{0.5f * Wp[r0 * H_ + j],   0.5f * Wp[r1 * H_ + j]};
        }
        const float br = bi1[j], bz = bi1[64 + j], bn = bi1[128 + j];
        const float bpv = 0.5f * bp[j];

        #pragma unroll 1
        for (int t = 0; t < T_; ++t) {
            if ((t & 7) == 0 && t >= DEPTH) waitge(&pv[1], t - 8);
            const float* xr = &xsh[(t >> 4) & 1][(t & 15) << 4];
            const float4 q0 = ((const float4*)xr)[0];
            const float4 q1 = ((const float4*)xr)[1];
            const float4 q2 = ((const float4*)xr)[2];
            const float4 q3 = ((const float4*)xr)[3];
            const v2f xp[8] = { v2f{q0.x, q0.y}, v2f{q0.z, q0.w},
                                v2f{q1.x, q1.y}, v2f{q1.z, q1.w},
                                v2f{q2.x, q2.y}, v2f{q2.z, q2.w},
                                v2f{q3.x, q3.y}, v2f{q3.z, q3.w} };
            v2f Ar = v2f{0.f, 0.f}, Az = v2f{0.f, 0.f};
            v2f An = v2f{0.f, 0.f}, Ap = v2f{0.f, 0.f};
            #pragma unroll
            for (int m = 0; m < 8; ++m) {
                Ar = fma2(xp[m], a1r[m], Ar);
                Az = fma2(xp[m], a1z[m], Az);
                An = fma2(xp[m], a1n[m], An);
                Ap = fma2(xp[m], apv[m], Ap);
            }
            const int sl = t & (DEPTH - 1);
            xg[sl][0][j] = Ar.x + Ar.y + br;
            xg[sl][1][j] = Az.x + Az.y + bz;
            xg[sl][2][j] = An.x + An.y + bn;
            xg[sl][3][j] = Ap.x + Ap.y + bpv;
            if ((t & 15) == 8) {
                const int c = (t >> 4) + 1;
                if (c < T_ / 16) {
                    ((float4*)&xsh[c & 1][0])[j] = xnext;
                    if (c + 1 < T_ / 16) xnext = ((const float4*)xb)[(c + 1) * 64 + j];
                }
            }
            LGKM0();
            if (j == 0) pv[0] = t + 1;
        }
    } else if (w == 1) {
        // ================= W1: L1 hidden + pointwise =================
        v2f wr[32], wz[32], wn[32];
        #pragma unroll
        for (int m = 0; m < 32; ++m) {
            const int r0 = 2 * m, r1 = r0 + 1;
            wr[m] = v2f{Whr1[r0 * H_ + j], Whr1[r1 * H_ + j]};
            wz[m] = v2f{Whz1[r0 * H_ + j], Whz1[r1 * H_ + j]};
            wn[m] = v2f{Whn1[r0 * H_ + j], Whn1[r1 * H_ + j]};
        }
        const float bh1 = bhn1[j];
        float h1j = 0.f;

        #pragma unroll 1
        for (int t = 0; t < T_; ++t) {
            if ((t & 7) == 0) {
                waitge(&pv[0], (t + 8 <= T_) ? t + 8 : T_);
                if (t >= DEPTH) { waitge(&pv[2], t - 8); waitge(&pv[3], t - 8); }
            }
            const int sl = t & (DEPTH - 1);
            const float xr_ = xg[sl][0][j];
            const float xz_ = xg[sl][1][j];
            const float xn_ = xg[sl][2][j];
            const float xp_ = xg[sl][3][j];
            const float* hb = h1b[(t + 1) & 1];        // h1(t-1)
            v2f Ar = v2f{0.f, 0.f}, Az = v2f{0.f, 0.f}, Ah = v2f{0.f, 0.f};
            #pragma unroll
            for (int q = 0; q < 16; ++q) {
                const float4 a = ((const float4*)hb)[q];
                const v2f h0 = v2f{a.x, a.y}, h1v = v2f{a.z, a.w};
                Ar = fma2(h0, wr[2 * q], Ar); Ar = fma2(h1v, wr[2 * q + 1], Ar);
                Az = fma2(h0, wz[2 * q], Az); Az = fma2(h1v, wz[2 * q + 1], Az);
                Ah = fma2(h0, wn[2 * q], Ah); Ah = fma2(h1v, wn[2 * q + 1], Ah);
            }
            const float r1 = sigm(Ar.x + Ar.y + xr_);
            const float z1 = sigm(Az.x + Az.y + xz_);
            const float n1 = tanh_(xn_ + r1 * (Ah.x + Ah.y + bh1));
            h1j = n1 + z1 * (h1j - n1);
            const float o1j = h1j + xp_;               // xp_ = 0.5(x@Wp+bp)
            h1b[t & 1][j] = h1j;
            o1r[sl][j] = o1j;
            LGKM0();
            if (j == 0) pv[1] = t + 1;
        }
    } else if (w == 2) {
        // ================= W2: pin = o1 @ Wi2 + bi2 =================
        v2f ur[32], uz[32], un[32];
        #pragma unroll
        for (int m = 0; m < 32; ++m) {
            const int r0 = 2 * m, r1 = r0 + 1;
            ur[m] = v2f{Wi2[r0 * 192 + j],       Wi2[r1 * 192 + j]};
            uz[m] = v2f{Wi2[r0 * 192 + 64 + j],  Wi2[r1 * 192 + 64 + j]};
            un[m] = v2f{Wi2[r0 * 192 + 128 + j], Wi2[r1 * 192 + 128 + j]};
        }
        const float cr = bi2[j], cz = bi2[64 + j], cn = bi2[128 + j];

        #pragma unroll 1
        for (int t = 0; t < T_; ++t) {
            waitge(&pv[1], t + 1);
            if ((t & 7) == 0 && t >= DEPTH) waitge(&pv[3], t - 8);
            const int sl = t & (DEPTH - 1);
            const float* orow = o1r[sl];
            v2f Pr = v2f{0.f, 0.f}, Pz = v2f{0.f, 0.f}, Pn = v2f{0.f, 0.f};
            #pragma unroll
            for (int q = 0; q < 16; ++q) {
                const float4 a = ((const float4*)orow)[q];
                const v2f o0 = v2f{a.x, a.y}, o1v = v2f{a.z, a.w};
                Pr = fma2(o0, ur[2 * q], Pr); Pr = fma2(o1v, ur[2 * q + 1], Pr);
                Pz = fma2(o0, uz[2 * q], Pz); Pz = fma2(o1v, uz[2 * q + 1], Pz);
                Pn = fma2(o0, un[2 * q], Pn); Pn = fma2(o1v, un[2 * q + 1], Pn);
            }
            pnr[sl][0][j] = Pr.x + Pr.y + cr;
            pnr[sl][1][j] = Pz.x + Pz.y + cz;
            pnr[sl][2][j] = Pn.x + Pn.y + cn;
            LGKM0();
            if (j == 0) pv[2] = t + 1;
        }
    } else {
        // ============= W3: L2 hidden + pointwise + online softmax =============
        v2f vr[32], vz[32], vn[32];
        #pragma unroll
        for (int m = 0; m < 32; ++m) {
            const int r0 = 2 * m, r1 = r0 + 1;
            vr[m] = v2f{Whr2[r0 * H_ + j], Whr2[r1 * H_ + j]};
            vz[m] = v2f{Whz2[r0 * H_ + j], Whz2[r1 * H_ + j]};
            vn[m] = v2f{Whn2[r0 * H_ + j], Whn2[r1 * H_ + j]};
        }
        const float ch2 = bhn2[j], waj = Wa[j];
        float h2j = 0.f, am = -3.0e38f, al = 0.f, aa = 0.f;

        #pragma unroll 1
        for (int t = 0; t < T_; ++t) {
            waitge(&pv[2], t + 1);   // implies o1(t) valid (transitive via W2)
            const int sl = t & (DEPTH - 1);
            const float pr = pnr[sl][0][j];
            const float pz = pnr[sl][1][j];
            const float pn = pnr[sl][2][j];
            const float o1j = o1r[sl][j];
            const float* hb = h2b[(t + 1) & 1];        // h2(t-1)
            v2f Ar = v2f{0.f, 0.f}, Az = v2f{0.f, 0.f}, Ah = v2f{0.f, 0.f};
            #pragma unroll
            for (int q = 0; q < 16; ++q) {
                const float4 a = ((const float4*)hb)[q];
                const v2f h0 = v2f{a.x, a.y}, h1v = v2f{a.z, a.w};
                Ar = fma2(h0, vr[2 * q], Ar); Ar = fma2(h1v, vr[2 * q + 1], Ar);
                Az = fma2(h0, vz[2 * q], Az); Az = fma2(h1v, vz[2 * q + 1], Az);
                Ah = fma2(h0, vn[2 * q], Ah); Ah = fma2(h1v, vn[2 * q + 1], Ah);
            }
            const float r2 = sigm(Ar.x + Ar.y + pr);
            const float z2 = sigm(Az.x + Az.y + pz);
            const float n2 = tanh_(pn + r2 * (Ah.x + Ah.y + ch2));
            h2j = n2 + z2 * (h2j - n2);
            const float o2j = h2j + 0.5f * o1j;
            h2b[t & 1][j] = h2j;
            // online softmax, in-wave, no skew
            float p = wred(o2j * waj);
            p = rdlane(p, 63);
            const float mn = fmaxf(am, p);
            const float ca = __builtin_amdgcn_exp2f((am - mn) * L2E);
            const float ce = __builtin_amdgcn_exp2f((p  - mn) * L2E);
            al = fmaf(al, ca, ce);
            aa = fmaf(aa, ca, ce * o2j);
            am = mn;
            LGKM0();                 // h2b write complete before next-iter read
            if (j == 0) pv[3] = t + 1;
        }
        sm_a[j] = aa / al;           // attended vector
    }

    __syncthreads();

    // ---- MLP tail (once per block) ----
    float v1 = 0.f;
    if (tid < 128) {
        float a = b1[tid];
        for (int k = 0; k < 64; ++k) a = fmaf(sm_a[k], W1[k * 128 + tid], a);
        v1 = fmaxf(a, 0.f);
    }
    __syncthreads();
    if (tid < 128) sm_b[tid] = v1;
    __syncthreads();
    if (tid < 64) {
        float a = b2[tid];
        for (int k = 0; k < 128; ++k) a = fmaf(sm_b[k], W2[k * 64 + tid], a);
        sm_a[tid] = fmaxf(a, 0.f);
    }
    __syncthreads();
    if (tid < 32) {
        float a = b3[tid];
        for (int k = 0; k < 64; ++k) a = fmaf(sm_a[k], W3[k * 32 + tid], a);
        sm_b[tid] = fmaxf(a, 0.f);
    }
    __syncthreads();
    if (tid < 2) {
        float a = b4[tid];
        for (int k = 0; k < 32; ++k) a = fmaf(sm_b[k], W4[k * 2 + tid], a);
        out[b * 2 + tid] = a;
    }
}

extern "C" void kernel_launch(void* const* d_in, const int* in_sizes, int n_in,
                              void* d_out, int out_size, void* d_ws, size_t ws_size,
                              hipStream_t stream) {
    const float* x    = (const float*)d_in[0];
    const float* Wi1  = (const float*)d_in[1];
    const float* bi1  = (const float*)d_in[2];
    const float* Whr1 = (const float*)d_in[3];
    const float* Whz1 = (const float*)d_in[4];
    const float* Whn1 = (const float*)d_in[5];
    const float* bhn1 = (const float*)d_in[6];
    const float* Wi2  = (const float*)d_in[7];
    const float* bi2  = (const float*)d_in[8];
    const float* Whr2 = (const float*)d_in[9];
    const float* Whz2 = (const float*)d_in[10];
    const float* Whn2 = (const float*)d_in[11];
    const float* bhn2 = (const float*)d_in[12];
    const float* Wp   = (const float*)d_in[13];
    const float* bp   = (const float*)d_in[14];
    const float* Wa   = (const float*)d_in[15];
    // d_in[16] = ba: softmax shift-invariant, unused
    const float* W1   = (const float*)d_in[17];
    const float* b1   = (const float*)d_in[18];
    const float* W2   = (const float*)d_in[19];
    const float* b2   = (const float*)d_in[20];
    const float* W3   = (const float*)d_in[21];
    const float* b3   = (const float*)d_in[22];
    const float* W4   = (const float*)d_in[23];
    const float* b4   = (const float*)d_in[24];

    solar_rnn<<<dim3(B_), dim3(256), 0, stream>>>(
        x, Wi1, bi1, Whr1, Whz1, Whn1, bhn1,
        Wi2, bi2, Whr2, Whz2, Whn2, bhn2,
        Wp, bp, Wa, W1, b1, W2, b2, W3, b3, W4, b4,
        (float*)d_out);
}